// Round 3
// baseline (418.888 us; speedup 1.0000x reference)
//
#include <hip/hip_runtime.h>

// RMSNorm (fp32 accum) + dynamic per-token int8 quantization.
// Harness dtype model (deduced R0-R2): fp16 inputs are converted by the
// harness to FLOAT32 ("float32 -> const float*"; fp16 is not in its cast
// list). Outputs (int8, f32) are not bf16 -> d_out is FLOAT32 ("else
// float*"): q-values [rows*H] then per-row scale [rows], flat f32.
//
// One block (256 threads) per row of H=4096; 16 elems/thread via 4x float4
// (coalesced 16B/lane). Single pass: sumsq(x) and max|x*w| together
// (rsqrt>0 so max|xn| = r*max|x*w|); p = x*w stays in registers.
// q = round(xn/scale) = round(p * 127/max|p|) — the rsqrt cancels exactly.

#define HDIM  4096
#define BLOCK 256
#define PER_T (HDIM / BLOCK)   // 16

__global__ __launch_bounds__(BLOCK) void qrms_kernel(
    const float* __restrict__ x,
    const float* __restrict__ w,
    float* __restrict__ qout,
    float* __restrict__ sout)
{
    const int row = blockIdx.x;
    const int t   = threadIdx.x;
    const float* xr = x + (size_t)row * HDIM;

    float p[PER_T];          // x*w, kept for quantize pass
    float sumsq = 0.0f;
    float amax  = 0.0f;

    #pragma unroll
    for (int c = 0; c < 4; ++c) {
        const int idx = c * (HDIM / 4) + t * 4;   // 4 chunks of 1024
        const float4 xv = *reinterpret_cast<const float4*>(xr + idx);
        const float4 wv = *reinterpret_cast<const float4*>(w  + idx);
        sumsq = fmaf(xv.x, xv.x, sumsq);
        sumsq = fmaf(xv.y, xv.y, sumsq);
        sumsq = fmaf(xv.z, xv.z, sumsq);
        sumsq = fmaf(xv.w, xv.w, sumsq);
        const float p0 = xv.x * wv.x;
        const float p1 = xv.y * wv.y;
        const float p2 = xv.z * wv.z;
        const float p3 = xv.w * wv.w;
        p[c * 4 + 0] = p0;
        p[c * 4 + 1] = p1;
        p[c * 4 + 2] = p2;
        p[c * 4 + 3] = p3;
        amax = fmaxf(amax, fmaxf(fmaxf(fabsf(p0), fabsf(p1)),
                                 fmaxf(fabsf(p2), fabsf(p3))));
    }

    // wave-64 butterfly reduction (sum + max together)
    #pragma unroll
    for (int off = 32; off > 0; off >>= 1) {
        sumsq += __shfl_xor(sumsq, off, 64);
        amax   = fmaxf(amax, __shfl_xor(amax, off, 64));
    }

    __shared__ float s_sum[BLOCK / 64];
    __shared__ float s_max[BLOCK / 64];
    const int wave = t >> 6;
    if ((t & 63) == 0) { s_sum[wave] = sumsq; s_max[wave] = amax; }
    __syncthreads();
    const float total = (s_sum[0] + s_sum[1]) + (s_sum[2] + s_sum[3]);
    const float mx    = fmaxf(fmaxf(s_max[0], s_max[1]), fmaxf(s_max[2], s_max[3]));

    const float r      = rsqrtf(total * (1.0f / HDIM) + 1e-6f);
    const float rowmax = mx * r;               // max|xn|
    const float qmul   = 127.0f / mx;          // p*qmul == xn/scale up to ulps

    if (t == 0) sout[row] = rowmax * (1.0f / 127.0f);

    float* qr = qout + (size_t)row * HDIM;
    #pragma unroll
    for (int c = 0; c < 4; ++c) {
        const int idx = c * (HDIM / 4) + t * 4;
        float q[4];
        #pragma unroll
        for (int k = 0; k < 4; ++k) {
            float v = rintf(p[c * 4 + k] * qmul);
            q[k] = fminf(127.0f, fmaxf(-128.0f, v));
        }
        *reinterpret_cast<float4*>(qr + idx) = make_float4(q[0], q[1], q[2], q[3]);
    }
}

extern "C" void kernel_launch(void* const* d_in, const int* in_sizes, int n_in,
                              void* d_out, int out_size, void* d_ws, size_t ws_size,
                              hipStream_t stream) {
    const float* x = (const float*)d_in[0];
    const float* w = (const float*)d_in[1];
    float* out = (float*)d_out;
    const int rows = in_sizes[0] / HDIM;           // B*S = 16384
    float* qout = out;
    float* sout = out + (size_t)in_sizes[0];       // scales after the q block
    qrms_kernel<<<dim3(rows), dim3(BLOCK), 0, stream>>>(x, w, qout, sout);
}